// Round 5
// baseline (109.086 us; speedup 1.0000x reference)
//
#include <hip/hip_runtime.h>
#include <hip/hip_bf16.h>
#include <hip/hip_cooperative_groups.h>

namespace cg = cooperative_groups;

#define DX 128
#define DH 128
#define HID 512
#define NB 4096
#define ROWS 16
#define OUTC 129   // 128 v cols + 1 div col

typedef __attribute__((ext_vector_type(4))) float f32x4;
typedef __attribute__((ext_vector_type(2))) float float2v;
typedef __attribute__((ext_vector_type(8))) short bf16x8;
typedef __attribute__((ext_vector_type(2))) short bf16x2;

// RNE float -> bf16 (bit pattern in a short)
__device__ inline short f2bf(float f) {
    unsigned u = __float_as_uint(f);
    unsigned r = (u + 0x7fffu + ((u >> 16) & 1u)) >> 16;
    return (short)r;
}

__device__ inline float fast_tanh(float x) {
    float e = __expf(2.0f * x);
    float r = __builtin_amdgcn_rcpf(e + 1.0f);
    return 1.0f - 2.0f * r;
}

// ---- single cooperative kernel: prep phase -> grid.sync -> cvf phase ----
// Prep (262144 threads, 1 elem each):
//   W1P layout: [nt(32)][ks(8)][lane(64)][e(8)] -> W1[(ks*32+(l>>4)*8+e), nt*16+(l&15)]
//   W2P layout: [nt(8)][ks(16)][lane(64)][e(8)] -> W2[(ks*32+(l>>4)*8+e), nt*16+(l&15)]
//   c[k] = sum_i W1[i,k]*W2[k,i]   (64 lanes per k, shuffle reduce)
// CVF (16 rows/block, 16 waves):
//   GEMM1: wave w owns hidden cols [w*32, w*32+32)
//   GEMM2: wave pair (2m,2m+1) owns out cols [m*16,m*16+16), K split even/odd
__global__ __launch_bounds__(1024) void fused_kernel(
    const float* __restrict__ state, const float* __restrict__ h_,
    const float* __restrict__ hn_, const float* __restrict__ tptr,
    const float* __restrict__ gsptr, const float* __restrict__ W1,
    const float* __restrict__ b1, const float* __restrict__ b2,
    const float* __restrict__ W2,
    float* __restrict__ c, short* __restrict__ w1p, short* __restrict__ w2p,
    float* __restrict__ out)
{
    __shared__ short xb [ROWS][DX  + 8];
    __shared__ short hb [ROWS][DH  + 8];
    __shared__ short hnb[ROWS][DH  + 8];
    __shared__ short ab_h[ROWS][HID + 8];
    __shared__ short ab_n[ROWS][HID + 8];
    __shared__ float divp[2][16][ROWS];
    __shared__ float red[8][2][64][4];   // [pair][branch][lane][q]

    const int tid  = threadIdx.x;
    const int lane = tid & 63;
    const int w    = tid >> 6;         // wave 0..15
    const int l15  = lane & 15;
    const int l4   = lane >> 4;
    const int row0 = blockIdx.x * ROWS;

    // ================= PREP PHASE =================
    {
        int tg = blockIdx.x * 1024 + tid;          // 0..262143
        if (tg < 131072) {                         // W1P pack
            int i  = tg;
            int nt = i >> 12;
            int ks = (i >> 9) & 7;
            int l  = (i >> 3) & 63;
            int e  = i & 7;
            int m  = ks * 32 + ((l >> 4) << 3) + e;
            int n  = nt * 16 + (l & 15);
            w1p[i] = f2bf(W1[m * HID + n]);
        } else if (tg < 196608) {                  // W2P pack
            int i  = tg - 131072;
            int nt = i >> 13;
            int ks = (i >> 9) & 15;
            int l  = (i >> 3) & 63;
            int e  = i & 7;
            int k  = ks * 32 + ((l >> 4) << 3) + e;
            int n  = nt * 16 + (l & 15);
            w2p[i] = f2bf(W2[k * DX + n]);
        } else if (tg < 229376) {                  // c[k], 64 lanes per k (wave-aligned)
            int r  = tg - 196608;
            int k  = r >> 6;
            int i0 = r & 63;
            float p = W1[i0 * HID + k] * W2[k * DX + i0]
                    + W1[(i0 + 64) * HID + k] * W2[k * DX + i0 + 64];
            for (int m = 1; m < 64; m <<= 1) p += __shfl_xor(p, m, 64);
            if (i0 == 0) c[k] = p;
        }
    }
    __threadfence();                 // cross-XCD visibility of w1p/w2p/c (G16)
    cg::this_grid().sync();

    // ================= CVF PHASE (identical math to R4) =================
    const float t  = tptr[0];
    const float gs = gsptr[0];

    // ---- prefetch: ALL 8 x-part B-frags + bias/t-col fold ----
    bf16x8 bx[2][4];
    float base[2];
    #pragma unroll
    for (int j = 0; j < 2; ++j) {
        #pragma unroll
        for (int ks = 0; ks < 4; ++ks)
            bx[j][ks] = *(const bf16x8*)&w1p[(((w * 2 + j) * 8 + ks) * 64 + lane) * 8];
        int k = w * 32 + j * 16 + l15;
        base[j] = b1[k] + t * W1[256 * HID + k];
    }

    // ---- stage x / h / h_null as bf16 into LDS (1024 threads: 2 floats each) ----
    {
        int r  = tid >> 6;            // 0..15
        int c0 = (tid & 63) * 2;      // 0..126
        const float* sp = state + (row0 + r) * OUTC + c0;   // x = state[:, :128]
        float2v vh = *(const float2v*)(h_  + (row0 + r) * DH + c0);
        float2v vn = *(const float2v*)(hn_ + (row0 + r) * DH + c0);
        bf16x2 sx, sh, sn;
        for (int e = 0; e < 2; ++e) {
            sx[e] = f2bf(sp[e]);
            sh[e] = f2bf(vh[e]);
            sn[e] = f2bf(vn[e]);
        }
        *(bf16x2*)&xb [r][c0] = sx;
        *(bf16x2*)&hb [r][c0] = sh;
        *(bf16x2*)&hnb[r][c0] = sn;
    }
    __syncthreads();

    // ---- GEMM1: pre = [x|h|t] @ W1 + b1 ----
    f32x4 acc_h[2], acc_n[2];
    {
        bf16x8 ax[4];
        #pragma unroll
        for (int ks = 0; ks < 4; ++ks)
            ax[ks] = *(const bf16x8*)&xb[l15][ks * 32 + l4 * 8];

        f32x4 accx[2];
        #pragma unroll
        for (int j = 0; j < 2; ++j)
            accx[j] = (f32x4){base[j], base[j], base[j], base[j]};
        #pragma unroll
        for (int ks = 0; ks < 4; ++ks)
            #pragma unroll
            for (int j = 0; j < 2; ++j)
                accx[j] = __builtin_amdgcn_mfma_f32_16x16x32_bf16(ax[ks], bx[j][ks], accx[j], 0, 0, 0);

        bf16x8 bh[2][4];
        #pragma unroll
        for (int j = 0; j < 2; ++j)
            #pragma unroll
            for (int ks = 0; ks < 4; ++ks)
                bh[j][ks] = *(const bf16x8*)&w1p[(((w * 2 + j) * 8 + 4 + ks) * 64 + lane) * 8];
        bf16x8 ah[4], an[4];
        #pragma unroll
        for (int ks = 0; ks < 4; ++ks) {
            ah[ks] = *(const bf16x8*)&hb [l15][ks * 32 + l4 * 8];
            an[ks] = *(const bf16x8*)&hnb[l15][ks * 32 + l4 * 8];
        }

        #pragma unroll
        for (int j = 0; j < 2; ++j) { acc_h[j] = accx[j]; acc_n[j] = accx[j]; }
        #pragma unroll
        for (int ks = 0; ks < 4; ++ks)
            #pragma unroll
            for (int j = 0; j < 2; ++j) {
                acc_h[j] = __builtin_amdgcn_mfma_f32_16x16x32_bf16(ah[ks], bh[j][ks], acc_h[j], 0, 0, 0);
                acc_n[j] = __builtin_amdgcn_mfma_f32_16x16x32_bf16(an[ks], bh[j][ks], acc_n[j], 0, 0, 0);
            }
    }

    // ---- prefetch GEMM2 B-frags: latency hides under epilogue A ----
    const int nt2 = w >> 1;
    const int ks0 = (w & 1) * 8;
    bf16x8 b2f[8];
    #pragma unroll
    for (int ks = 0; ks < 8; ++ks)
        b2f[ks] = *(const bf16x8*)&w2p[((nt2 * 16 + ks0 + ks) * 64 + lane) * 8];

    // ---- epilogue A: a = tanh(pre) -> LDS (bf16); div partials (1-a^2)*c[k] ----
    float dph[4] = {0, 0, 0, 0}, dpn[4] = {0, 0, 0, 0};
    for (int j = 0; j < 2; ++j) {
        int k = w * 32 + j * 16 + l15;                    // D-frag col = lane&15
        float ck = c[k];
        for (int q = 0; q < 4; ++q) {
            int r = l4 * 4 + q;                           // D-frag row = (lane>>4)*4 + q
            float a1 = fast_tanh(acc_h[j][q]);
            float a2 = fast_tanh(acc_n[j][q]);
            ab_h[r][k] = f2bf(a1);
            ab_n[r][k] = f2bf(a2);
            dph[q] += (1.f - a1 * a1) * ck;
            dpn[q] += (1.f - a2 * a2) * ck;
        }
    }
    for (int q = 0; q < 4; ++q) {
        for (int m = 1; m < 16; m <<= 1) {
            dph[q] += __shfl_xor(dph[q], m, 64);
            dpn[q] += __shfl_xor(dpn[q], m, 64);
        }
    }
    if (l15 == 0) {
        for (int q = 0; q < 4; ++q) {
            divp[0][w][l4 * 4 + q] = dph[q];
            divp[1][w][l4 * 4 + q] = dpn[q];
        }
    }
    __syncthreads();

    // ---- GEMM2 (K-split): wave pair (2m,2m+1) -> out cols [m*16,m*16+16) ----
    f32x4 avh = (f32x4){0, 0, 0, 0}, avn = (f32x4){0, 0, 0, 0};
    #pragma unroll
    for (int ks = 0; ks < 8; ++ks) {
        bf16x8 afh = *(const bf16x8*)&ab_h[l15][(ks0 + ks) * 32 + l4 * 8];
        bf16x8 afn = *(const bf16x8*)&ab_n[l15][(ks0 + ks) * 32 + l4 * 8];
        avh = __builtin_amdgcn_mfma_f32_16x16x32_bf16(afh, b2f[ks], avh, 0, 0, 0);
        avn = __builtin_amdgcn_mfma_f32_16x16x32_bf16(afn, b2f[ks], avn, 0, 0, 0);
    }
    if (w & 1) {
        for (int q = 0; q < 4; ++q) {
            red[w >> 1][0][lane][q] = avh[q];
            red[w >> 1][1][lane][q] = avn[q];
        }
    }
    __syncthreads();

    // ---- epilogue B: even waves combine partials, blend + bias, write v ----
    if (!(w & 1)) {
        int col = (w >> 1) * 16 + l15;
        float bb = b2[col];
        for (int q = 0; q < 4; ++q) {
            int r = l4 * 4 + q;
            float vh = avh[q] + red[w >> 1][0][lane][q];
            float vn = avn[q] + red[w >> 1][1][lane][q];
            float v = (1.f - gs) * vn + gs * vh + bb;
            out[(row0 + r) * OUTC + col] = v;
        }
    }

    // ---- div: sum wave partials, blend, write col 128 ----
    if (tid < ROWS) {
        float dh = 0.f, dn = 0.f;
        for (int ww = 0; ww < 16; ++ww) { dh += divp[0][ww][tid]; dn += divp[1][ww][tid]; }
        out[(row0 + tid) * OUTC + DX] = (1.f - gs) * dn + gs * dh;
    }
}

extern "C" void kernel_launch(void* const* d_in, const int* in_sizes, int n_in,
                              void* d_out, int out_size, void* d_ws, size_t ws_size,
                              hipStream_t stream) {
    const float* state = (const float*)d_in[0];
    const float* h     = (const float*)d_in[1];
    const float* hn    = (const float*)d_in[2];
    const float* t     = (const float*)d_in[3];
    const float* gs    = (const float*)d_in[4];
    const float* W1    = (const float*)d_in[5];
    const float* b1    = (const float*)d_in[6];
    const float* W2    = (const float*)d_in[7];
    const float* b2    = (const float*)d_in[8];
    float* out = (float*)d_out;

    // workspace layout: c (512 f32) | W1P (131072 bf16) | W2P (65536 bf16)  ~= 390 KB
    float* c   = (float*)d_ws;
    short* w1p = (short*)((char*)d_ws + 2048);
    short* w2p = (short*)((char*)d_ws + 2048 + 262144);

    void* args[] = {
        (void*)&state, (void*)&h, (void*)&hn, (void*)&t, (void*)&gs,
        (void*)&W1, (void*)&b1, (void*)&b2, (void*)&W2,
        (void*)&c, (void*)&w1p, (void*)&w2p, (void*)&out
    };
    hipLaunchCooperativeKernel((void*)fused_kernel, dim3(NB / ROWS), dim3(1024),
                               args, 0, stream);
}

// Round 6
// 18.506 us; speedup vs baseline: 5.8947x; 5.8947x over previous
//
#include <hip/hip_runtime.h>
#include <hip/hip_bf16.h>

#define DX 128
#define DH 128
#define HID 512
#define NB 4096
#define ROWS 16
#define OUTC 129   // 128 v cols + 1 div col

typedef __attribute__((ext_vector_type(4))) float f32x4;
typedef __attribute__((ext_vector_type(2))) float float2v;
typedef __attribute__((ext_vector_type(8))) short bf16x8;
typedef __attribute__((ext_vector_type(2))) short bf16x2;

// RNE float -> bf16 (bit pattern in a short)
__device__ inline short f2bf(float f) {
    unsigned u = __float_as_uint(f);
    unsigned r = (u + 0x7fffu + ((u >> 16) & 1u)) >> 16;
    return (short)r;
}

__device__ inline float fast_tanh(float x) {
    float e = __expf(2.0f * x);
    float r = __builtin_amdgcn_rcpf(e + 1.0f);
    return 1.0f - 2.0f * r;
}

// -------- prep v2: wave-per-tile coalesced repack --------
// W1P layout: [nt(32)][ks(8)][lane(64)][e(8)] -> W1[(ks*32+(l>>4)*8+e), nt*16+(l&15)]
// W2P layout: [nt(8)][ks(16)][lane(64)][e(8)] -> W2[(ks*32+(l>>4)*8+e), nt*16+(l&15)]
// Wave roles (global wave id W = blockIdx.x*4 + w):
//   W <  256 : pack one w1p tile (nt = W>>3, ks = W&7): 32 m-rows x 16 n-cols
//   W <  384 : pack one w2p tile (idx = W-256; nt = idx>>4, ks = idx&15)
//   W <  896 : c[k] for k = W-384 (wave-parallel dot + shuffle reduce)
__global__ __launch_bounds__(256) void prep_kernel(
    const float* __restrict__ W1, const float* __restrict__ W2,
    float* __restrict__ c, short* __restrict__ w1p, short* __restrict__ w2p)
{
    __shared__ float tile[4][32][17];   // wave-private padded tiles (+1 dword: <=2-way banks)

    const int tid  = threadIdx.x;
    const int lane = tid & 63;
    const int w    = tid >> 6;
    const int l15  = lane & 15;
    const int l4   = lane >> 4;
    const int W    = blockIdx.x * 4 + w;

    // phase 1: stage a 32x16 fp32 tile, fully coalesced (16 floats = one 64B line per group)
    if (W < 256) {                         // w1p tile
        int nt = W >> 3, ks = W & 7;
        int m0 = ks * 32, n0 = nt * 16;
        #pragma unroll
        for (int p = 0; p < 8; ++p) {
            int r = p * 4 + l4;
            tile[w][r][l15] = W1[(m0 + r) * HID + n0 + l15];
        }
    } else if (W < 384) {                  // w2p tile
        int idx = W - 256;
        int nt = idx >> 4, ks = idx & 15;
        int k0 = ks * 32, n0 = nt * 16;
        #pragma unroll
        for (int p = 0; p < 8; ++p) {
            int r = p * 4 + l4;
            tile[w][r][l15] = W2[(k0 + r) * DX + n0 + l15];
        }
    }
    __syncthreads();

    // phase 2: emit packed bf16 run — 1 KB per wave, perfectly coalesced
    if (W < 256) {
        bf16x8 v;
        #pragma unroll
        for (int e = 0; e < 8; ++e) v[e] = f2bf(tile[w][l4 * 8 + e][l15]);
        *(bf16x8*)&w1p[W * 512 + lane * 8] = v;
    } else if (W < 384) {
        int idx = W - 256;
        bf16x8 v;
        #pragma unroll
        for (int e = 0; e < 8; ++e) v[e] = f2bf(tile[w][l4 * 8 + e][l15]);
        *(bf16x8*)&w2p[idx * 512 + lane * 8] = v;
    } else if (W < 896) {                  // c[k] = sum_i W1[i,k]*W2[k,i]
        int k = W - 384;
        float p = W1[lane * HID + k] * W2[k * DX + lane]
                + W1[(lane + 64) * HID + k] * W2[k * DX + lane + 64];
        for (int m = 1; m < 64; m <<= 1) p += __shfl_xor(p, m, 64);
        if (lane == 0) c[k] = p;
    }
}

// -------- main fused kernel: 16 rows/block, 16 waves (identical to R4) ----
// GEMM1: wave w owns hidden cols [w*32, w*32+32)   (2 nt-tiles)
// GEMM2: wave pair (2m, 2m+1) owns out cols [m*16, m*16+16); even wave K=0..255,
//        odd wave K=256..511; partials reduced via LDS.
__global__ __launch_bounds__(1024) void cvf_kernel(
    const float* __restrict__ state, const float* __restrict__ h_,
    const float* __restrict__ hn_, const float* __restrict__ tptr,
    const float* __restrict__ gsptr, const float* __restrict__ W1,
    const float* __restrict__ b1, const float* __restrict__ b2,
    const float* __restrict__ c, const short* __restrict__ w1p,
    const short* __restrict__ w2p, float* __restrict__ out)
{
    __shared__ short xb [ROWS][DX  + 8];
    __shared__ short hb [ROWS][DH  + 8];
    __shared__ short hnb[ROWS][DH  + 8];
    __shared__ short ab_h[ROWS][HID + 8];
    __shared__ short ab_n[ROWS][HID + 8];
    __shared__ float divp[2][16][ROWS];
    __shared__ float red[8][2][64][4];   // [pair][branch][lane][q]

    const int tid  = threadIdx.x;
    const int lane = tid & 63;
    const int w    = tid >> 6;         // wave 0..15
    const int l15  = lane & 15;
    const int l4   = lane >> 4;
    const int row0 = blockIdx.x * ROWS;
    const float t  = tptr[0];
    const float gs = gsptr[0];

    // ---- prefetch: ALL 8 x-part B-frags + bias/t-col fold ----
    bf16x8 bx[2][4];
    float base[2];
    #pragma unroll
    for (int j = 0; j < 2; ++j) {
        #pragma unroll
        for (int ks = 0; ks < 4; ++ks)
            bx[j][ks] = *(const bf16x8*)&w1p[(((w * 2 + j) * 8 + ks) * 64 + lane) * 8];
        int k = w * 32 + j * 16 + l15;
        base[j] = b1[k] + t * W1[256 * HID + k];
    }

    // ---- stage x / h / h_null as bf16 into LDS (1024 threads: 2 floats each) ----
    {
        int r  = tid >> 6;            // 0..15
        int c0 = (tid & 63) * 2;      // 0..126
        const float* sp = state + (row0 + r) * OUTC + c0;   // x = state[:, :128]
        float2v vh = *(const float2v*)(h_  + (row0 + r) * DH + c0);
        float2v vn = *(const float2v*)(hn_ + (row0 + r) * DH + c0);
        bf16x2 sx, sh, sn;
        for (int e = 0; e < 2; ++e) {
            sx[e] = f2bf(sp[e]);
            sh[e] = f2bf(vh[e]);
            sn[e] = f2bf(vn[e]);
        }
        *(bf16x2*)&xb [r][c0] = sx;
        *(bf16x2*)&hb [r][c0] = sh;
        *(bf16x2*)&hnb[r][c0] = sn;
    }
    __syncthreads();

    // ---- GEMM1: pre = [x|h|t] @ W1 + b1 ----
    f32x4 acc_h[2], acc_n[2];
    {
        bf16x8 ax[4];
        #pragma unroll
        for (int ks = 0; ks < 4; ++ks)
            ax[ks] = *(const bf16x8*)&xb[l15][ks * 32 + l4 * 8];

        f32x4 accx[2];
        #pragma unroll
        for (int j = 0; j < 2; ++j)
            accx[j] = (f32x4){base[j], base[j], base[j], base[j]};
        #pragma unroll
        for (int ks = 0; ks < 4; ++ks)
            #pragma unroll
            for (int j = 0; j < 2; ++j)
                accx[j] = __builtin_amdgcn_mfma_f32_16x16x32_bf16(ax[ks], bx[j][ks], accx[j], 0, 0, 0);

        bf16x8 bh[2][4];
        #pragma unroll
        for (int j = 0; j < 2; ++j)
            #pragma unroll
            for (int ks = 0; ks < 4; ++ks)
                bh[j][ks] = *(const bf16x8*)&w1p[(((w * 2 + j) * 8 + 4 + ks) * 64 + lane) * 8];
        bf16x8 ah[4], an[4];
        #pragma unroll
        for (int ks = 0; ks < 4; ++ks) {
            ah[ks] = *(const bf16x8*)&hb [l15][ks * 32 + l4 * 8];
            an[ks] = *(const bf16x8*)&hnb[l15][ks * 32 + l4 * 8];
        }

        #pragma unroll
        for (int j = 0; j < 2; ++j) { acc_h[j] = accx[j]; acc_n[j] = accx[j]; }
        #pragma unroll
        for (int ks = 0; ks < 4; ++ks)
            #pragma unroll
            for (int j = 0; j < 2; ++j) {
                acc_h[j] = __builtin_amdgcn_mfma_f32_16x16x32_bf16(ah[ks], bh[j][ks], acc_h[j], 0, 0, 0);
                acc_n[j] = __builtin_amdgcn_mfma_f32_16x16x32_bf16(an[ks], bh[j][ks], acc_n[j], 0, 0, 0);
            }
    }

    // ---- prefetch GEMM2 B-frags: latency hides under epilogue A ----
    const int nt2 = w >> 1;
    const int ks0 = (w & 1) * 8;
    bf16x8 b2f[8];
    #pragma unroll
    for (int ks = 0; ks < 8; ++ks)
        b2f[ks] = *(const bf16x8*)&w2p[((nt2 * 16 + ks0 + ks) * 64 + lane) * 8];

    // ---- epilogue A: a = tanh(pre) -> LDS (bf16); div partials (1-a^2)*c[k] ----
    float dph[4] = {0, 0, 0, 0}, dpn[4] = {0, 0, 0, 0};
    for (int j = 0; j < 2; ++j) {
        int k = w * 32 + j * 16 + l15;                    // D-frag col = lane&15
        float ck = c[k];
        for (int q = 0; q < 4; ++q) {
            int r = l4 * 4 + q;                           // D-frag row = (lane>>4)*4 + q
            float a1 = fast_tanh(acc_h[j][q]);
            float a2 = fast_tanh(acc_n[j][q]);
            ab_h[r][k] = f2bf(a1);
            ab_n[r][k] = f2bf(a2);
            dph[q] += (1.f - a1 * a1) * ck;
            dpn[q] += (1.f - a2 * a2) * ck;
        }
    }
    for (int q = 0; q < 4; ++q) {
        for (int m = 1; m < 16; m <<= 1) {
            dph[q] += __shfl_xor(dph[q], m, 64);
            dpn[q] += __shfl_xor(dpn[q], m, 64);
        }
    }
    if (l15 == 0) {
        for (int q = 0; q < 4; ++q) {
            divp[0][w][l4 * 4 + q] = dph[q];
            divp[1][w][l4 * 4 + q] = dpn[q];
        }
    }
    __syncthreads();

    // ---- GEMM2 (K-split): wave pair (2m,2m+1) -> out cols [m*16,m*16+16) ----
    f32x4 avh = (f32x4){0, 0, 0, 0}, avn = (f32x4){0, 0, 0, 0};
    #pragma unroll
    for (int ks = 0; ks < 8; ++ks) {
        bf16x8 afh = *(const bf16x8*)&ab_h[l15][(ks0 + ks) * 32 + l4 * 8];
        bf16x8 afn = *(const bf16x8*)&ab_n[l15][(ks0 + ks) * 32 + l4 * 8];
        avh = __builtin_amdgcn_mfma_f32_16x16x32_bf16(afh, b2f[ks], avh, 0, 0, 0);
        avn = __builtin_amdgcn_mfma_f32_16x16x32_bf16(afn, b2f[ks], avn, 0, 0, 0);
    }
    if (w & 1) {
        for (int q = 0; q < 4; ++q) {
            red[w >> 1][0][lane][q] = avh[q];
            red[w >> 1][1][lane][q] = avn[q];
        }
    }
    __syncthreads();

    // ---- epilogue B: even waves combine partials, blend + bias, write v ----
    if (!(w & 1)) {
        int col = (w >> 1) * 16 + l15;
        float bb = b2[col];
        for (int q = 0; q < 4; ++q) {
            int r = l4 * 4 + q;
            float vh = avh[q] + red[w >> 1][0][lane][q];
            float vn = avn[q] + red[w >> 1][1][lane][q];
            float v = (1.f - gs) * vn + gs * vh + bb;
            out[(row0 + r) * OUTC + col] = v;
        }
    }

    // ---- div: sum wave partials, blend, write col 128 ----
    if (tid < ROWS) {
        float dh = 0.f, dn = 0.f;
        for (int ww = 0; ww < 16; ++ww) { dh += divp[0][ww][tid]; dn += divp[1][ww][tid]; }
        out[(row0 + tid) * OUTC + DX] = (1.f - gs) * dn + gs * dh;
    }
}

extern "C" void kernel_launch(void* const* d_in, const int* in_sizes, int n_in,
                              void* d_out, int out_size, void* d_ws, size_t ws_size,
                              hipStream_t stream) {
    const float* state = (const float*)d_in[0];
    const float* h     = (const float*)d_in[1];
    const float* hn    = (const float*)d_in[2];
    const float* t     = (const float*)d_in[3];
    const float* gs    = (const float*)d_in[4];
    const float* W1    = (const float*)d_in[5];
    const float* b1    = (const float*)d_in[6];
    const float* W2    = (const float*)d_in[7];
    const float* b2    = (const float*)d_in[8];
    float* out = (float*)d_out;

    // workspace layout: c (512 f32) | W1P (131072 bf16) | W2P (65536 bf16)  ~= 390 KB
    float* c   = (float*)d_ws;
    short* w1p = (short*)((char*)d_ws + 2048);
    short* w2p = (short*)((char*)d_ws + 2048 + 262144);

    prep_kernel<<<224, 256, 0, stream>>>(W1, W2, c, w1p, w2p);
    cvf_kernel<<<NB / ROWS, 1024, 0, stream>>>(state, h, hn, t, gs, W1, b1, b2, c, w1p, w2p, out);
}